// Round 8
// baseline (277.000 us; speedup 1.0000x reference)
//
#include <hip/hip_runtime.h>

constexpr int N_NODES = 100000;
constexpr int N_EDGES = 1000000;
constexpr int DIM = 64;

constexpr int BNODES = 256;                                  // nodes per bucket
constexpr int NBUCK  = (N_NODES + BNODES - 1) / BNODES;      // 391
constexpr int NSUB   = 8;                                    // sub-cursors per bucket
constexpr int SUBCAP = 448;                                  // per (bucket,sub) cap: lam=320, +7 sigma
constexpr int SCAP   = NSUB * SUBCAP;                        // 3584 pairs per bucket

constexpr int CAP  = 16;      // per-node neighbor slots in LDS; deg>16 -> fixup
constexpr int MAXO = 32768;   // overflow pair list

constexpr int TILE = 64;      // nodes per fused block
constexpr int PAD  = 65;      // LDS row stride (floats)

// --- Phase A: single-pass append into per-(bucket,sub) staging runs ---------
// r7's two-pass reservation scheme cost ~60-80us (2x edge reads, 7.6 waves/CU,
// 190K fragmented 20B store-runs). This version: ONE pass, max TLP (3907
// blocks), 1M atomics spread over 3128 cursors (~320 serialized per address,
// pipelined in L2), and stores append sequentially per (bucket,sub) region so
// sectors fill in temporal bursts. Sub-major cursor layout (gcur[s*NBUCK+bk])
// keeps a bucket's 8 cursors on different lines/L2 channels.
// Record: (i & 255) << 17 | j   (off 8b, j 17b; j < 100000 < 2^17).
__global__ __launch_bounds__(256) void bin_edges(
    const int* __restrict__ eidx, int* __restrict__ gcur,
    int* __restrict__ staging, int* __restrict__ noflow, int* __restrict__ oflow)
{
    int e = blockIdx.x * 256 + threadIdx.x;
    if (e >= N_EDGES) return;
    int i  = eidx[e];
    int j  = eidx[N_EDGES + e];
    int bk = i >> 8;
    int s  = blockIdx.x & (NSUB - 1);
    int pos = atomicAdd(&gcur[s * NBUCK + bk], 1);
    if (pos < SUBCAP) {
        staging[bk * SCAP + s * SUBCAP + pos] = ((i & 255) << 17) | j;
    } else {                                 // p ~ 0 at +7 sigma; exact fixup
        int o = atomicAdd(noflow, 1);
        if (o < MAXO) { oflow[2 * o] = i; oflow[2 * o + 1] = j; }
    }
}

// --- Phase B (fused): LDS slot-bin + gather mean + 64x64 matmul + bias ------
// Block = 256 threads = 4 waves, one 64-node tile = quarter of one bucket.
// KEY FIX vs r7: sched_barrier(0) between the 16-load loop and the accumulate
// loop. r7's explicit vb[16] was defeated by the instruction scheduler
// (VGPR=44: it interleaved load->accumulate and recycled registers, leaving
// ~3 loads in flight -> 84.5us latency-bound). The fence forces all 16
// global_load_dwordx4 to issue before any consume: 64 VGPRs genuinely in
// flight, gather latency fully hidden by ~28 waves/CU.
__global__ __launch_bounds__(256) void fused_gather_mm(
    const float* __restrict__ x, const int* __restrict__ gcur,
    const int* __restrict__ staging,
    const float* __restrict__ W, const float* __restrict__ b,
    int* __restrict__ noflow, int* __restrict__ oflow,
    int* __restrict__ deg_g, float* __restrict__ out)
{
    __shared__ float tile[TILE * PAD];       // 16.6 KB
    __shared__ int   lds_slot[TILE * CAP];   // 4 KB
    __shared__ int   lcnt[TILE];

    const int tid  = threadIdx.x;
    const int base = blockIdx.x * TILE;
    const int bk   = blockIdx.x >> 2;        // bucket (4 tiles per bucket)
    const int sub  = blockIdx.x & 3;         // which 64-node quarter

    if (tid < TILE) lcnt[tid] = 0;
    __syncthreads();

    // ---- bin staged pairs (8 sub-runs) for this tile's 64 nodes ----
    for (int ss = 0; ss < NSUB; ++ss) {
        int m = gcur[ss * NBUCK + bk];
        if (m > SUBCAP) m = SUBCAP;
        const int sg = bk * SCAP + ss * SUBCAP;
        for (int t = tid; t < m; t += 256) {
            int pk  = staging[sg + t];
            int off = pk >> 17;              // 0..255 within bucket
            if ((off >> 6) == sub) {
                int r = off & 63;
                int pos = atomicAdd(&lcnt[r], 1);
                if (pos < CAP) {
                    lds_slot[(r << 4) + pos] = pk & 0x1FFFF;
                } else {
                    int o = atomicAdd(noflow, 1);
                    if (o < MAXO) {
                        oflow[2 * o]     = (bk << 8) + off;   // global node id
                        oflow[2 * o + 1] = pk & 0x1FFFF;      // source j
                    }
                }
            }
        }
    }
    __syncthreads();

    // true degree out for the fixup kernel (coalesced 64-int write)
    if (tid < TILE) {
        int g = base + tid;
        if (g < N_NODES) deg_g[g] = lcnt[tid];
    }

    // ---- gather: 16-lane group per node, 4 nodes in flight per wave ----
    const int lane = tid & 63;
    const int wid  = tid >> 6;               // 0..3
    const int grp  = lane >> 4;              // 0..3
    const int l16  = lane & 15;
    const int c4   = l16 << 2;

#pragma unroll
    for (int pack = 0; pack < 4; ++pack) {
        const int row    = wid * 16 + pack * 4 + grp;   // 0..63
        const int d_true = lcnt[row];        // 0 for out-of-range nodes
        const int d      = (d_true < CAP) ? d_true : CAP;

        // 16 static-address LDS reads (broadcast in group, <=2-way = free)
        int jv[16];
#pragma unroll
        for (int u = 0; u < 16; ++u) jv[u] = lds_slot[(row << 4) + u];

        // 16 independent float4 loads — fence forces ALL issued before use
        float4 vb[16];
#pragma unroll
        for (int u = 0; u < 16; ++u) {
            const int jj = (u < d) ? jv[u] : 0;   // clamp: dummy hits row 0 (L1)
            vb[u] = *reinterpret_cast<const float4*>(x + ((size_t)jj << 6) + c4);
        }
        __builtin_amdgcn_sched_barrier(0);   // nothing crosses: 16 loads in flight

        float sx = 0.0f, sy = 0.0f, sz = 0.0f, sw = 0.0f;
#pragma unroll
        for (int u = 0; u < 16; ++u) {
            const bool ok = (u < d);
            sx += ok ? vb[u].x : 0.0f;
            sy += ok ? vb[u].y : 0.0f;
            sz += ok ? vb[u].z : 0.0f;
            sw += ok ? vb[u].w : 0.0f;
        }

        const float inv = (d_true > 0) ? 1.0f / (float)d_true : 0.0f;
        const int tb = row * PAD + c4;
        tile[tb + 0] = sx * inv;
        tile[tb + 1] = sy * inv;
        tile[tb + 2] = sz * inv;
        tile[tb + 3] = sw * inv;
    }
    __syncthreads();

    // ---- matmul: acc[q] = sum_k agg[nd][k] * W[d0+q][k] ----
    const int nd  = tid & 63;
    const int d0u = __builtin_amdgcn_readfirstlane((tid >> 6) << 4);
    const float* __restrict__ Wr = W + (size_t)d0u * DIM;   // uniform -> s_load

    float acc[16];
#pragma unroll
    for (int q = 0; q < 16; ++q) acc[q] = 0.0f;

#pragma unroll 4
    for (int k = 0; k < DIM; ++k) {
        float a = tile[nd * PAD + k];        // lane*65+k: conflict-free
#pragma unroll
        for (int q = 0; q < 16; ++q)
            acc[q] = fmaf(a, Wr[(size_t)q * DIM + k], acc[q]);
    }

    // ---- epilogue: mask + bias, LDS round-trip for coalesced store ----
    const int dg = lcnt[nd];
    __syncthreads();                         // everyone done reading agg
#pragma unroll
    for (int q = 0; q < 16; ++q) {
        float v = (dg > 0) ? (acc[q] + b[d0u + q]) : 0.0f;
        tile[nd * PAD + d0u + q] = v;
    }
    __syncthreads();

#pragma unroll
    for (int r = 0; r < 16; ++r) {
        int idx = r * 256 + tid;             // 0..4095
        int row = idx >> 6, d = idx & 63;
        int g = base + row;
        if (g < N_NODES)
            out[(size_t)g * DIM + d] = tile[row * PAD + d];
    }
}

// --- Phase C: exact fixup for deg>16 / staging overflow ---------------------
__global__ __launch_bounds__(256) void fixup_overflow(
    const int* __restrict__ noflow, const int* __restrict__ oflow,
    const int* __restrict__ deg_g, const float* __restrict__ x,
    const float* __restrict__ W, float* __restrict__ out)
{
    int m = *noflow;
    if (m > MAXO) m = MAXO;
    const int lane = threadIdx.x & 63;
    const int wv   = (blockIdx.x * 256 + threadIdx.x) >> 6;
    const int nwv  = (gridDim.x * 256) >> 6;
    const float* __restrict__ wr = W + ((size_t)lane << 6);
    for (int o = wv; o < m; o += nwv) {
        const int i = oflow[2 * o];
        const int j = oflow[2 * o + 1];
        const float inv = 1.0f / (float)deg_g[i];
        const float* __restrict__ xr = x + ((size_t)j << 6);
        float acc = 0.0f;
#pragma unroll
        for (int k4 = 0; k4 < 16; ++k4) {
            const float4 xv  = *reinterpret_cast<const float4*>(xr + 4 * k4);
            const float4 wv4 = *reinterpret_cast<const float4*>(wr + 4 * k4);
            acc = fmaf(xv.x, wv4.x, acc);
            acc = fmaf(xv.y, wv4.y, acc);
            acc = fmaf(xv.z, wv4.z, acc);
            acc = fmaf(xv.w, wv4.w, acc);
        }
        atomicAdd(&out[((size_t)i << 6) + lane], acc * inv);
    }
}

extern "C" void kernel_launch(void* const* d_in, const int* in_sizes, int n_in,
                              void* d_out, int out_size, void* d_ws, size_t ws_size,
                              hipStream_t stream) {
    const float* x  = (const float*)d_in[0];   // (N, 64)
    const int*   ei = (const int*)d_in[1];     // (2, E): [0,E) targets, [E,2E) sources
    const float* W  = (const float*)d_in[2];   // (64, 64)
    const float* b  = (const float*)d_in[3];   // (64,)
    float* out = (float*)d_out;                // (N, 64)

    // Workspace layout (~6.3 MB)
    int* gcur    = (int*)d_ws;                 // NSUB*NBUCK (memset with noflow)
    int* noflow  = gcur + NSUB * NBUCK;        // 1
    int* oflow   = noflow + 1;                 // 2*MAXO
    int* deg_g   = oflow + 2 * MAXO;           // N_NODES
    int* staging = deg_g + N_NODES;            // NBUCK * SCAP

    hipMemsetAsync(gcur, 0, (NSUB * NBUCK + 1) * sizeof(int), stream);

    bin_edges<<<(N_EDGES + 255) / 256, 256, 0, stream>>>(
        ei, gcur, staging, noflow, oflow);
    fused_gather_mm<<<(N_NODES + TILE - 1) / TILE, 256, 0, stream>>>(
        x, gcur, staging, W, b, noflow, oflow, deg_g, out);
    fixup_overflow<<<128, 256, 0, stream>>>(noflow, oflow, deg_g, x, W, out);
}

// Round 9
// 201.160 us; speedup vs baseline: 1.3770x; 1.3770x over previous
//
#include <hip/hip_runtime.h>

constexpr int N_NODES = 100000;
constexpr int N_EDGES = 1000000;
constexpr int DIM = 64;

constexpr int BNODES = 256;                                  // nodes per bucket
constexpr int NBUCK  = (N_NODES + BNODES - 1) / BNODES;      // 391
constexpr int SCAP   = 3072;                                 // pairs/bucket cap (lam=2558, +10 sigma)
constexpr int CHUNK  = 2048;                                 // edges per bin WG
constexpr int EPT    = 8;                                    // edges per thread
constexpr int NWG_A  = (N_EDGES + CHUNK - 1) / CHUNK;        // 489

constexpr int CAP  = 16;      // per-node neighbor slots; deg>16 -> exact fixup
constexpr int MAXO = 16384;   // overflow pair list (expected ~8k)

constexpr int TILE = 64;      // nodes per fused block
constexpr int PAD  = 65;      // LDS row stride (floats)

// --- Phase A: bucket-partition edges, ONE edge read, rank-from-histogram ----
// The pass-1 LDS histogram atomicAdd RETURNS each edge's rank within its
// (WG,bucket) run; keeping i/j/rank in registers lets pass-2 be pure stores.
// vs r7's two-pass: deletes the 2nd 8MB edge read and 1M pass-2 LDS atomics.
// Global atomics: one per (WG,bucket) with count>0 (~190K, over 391 addrs).
// Record: (i & 255) << 17 | j   (off 8b, j 17b; j < 100000 < 2^17).
__global__ __launch_bounds__(256) void bin_edges(
    const int* __restrict__ eidx, int* __restrict__ gcur,
    int* __restrict__ staging)
{
    __shared__ int hist[NBUCK];
    __shared__ int gbase[NBUCK];

    const int tid = threadIdx.x;
    const int e0  = blockIdx.x * CHUNK;

    for (int t = tid; t < NBUCK; t += 256) hist[t] = 0;

    int iv[EPT], jv[EPT], rk[EPT];
#pragma unroll
    for (int u = 0; u < EPT; ++u) {
        int e = e0 + u * 256 + tid;
        bool ok = (e < N_EDGES);
        iv[u] = ok ? eidx[e] : -1;
        jv[u] = ok ? eidx[N_EDGES + e] : 0;
    }
    __syncthreads();

#pragma unroll
    for (int u = 0; u < EPT; ++u)
        if (iv[u] >= 0) rk[u] = atomicAdd(&hist[iv[u] >> 8], 1);
    __syncthreads();

    for (int t = tid; t < NBUCK; t += 256) {
        int c = hist[t];
        gbase[t] = (c > 0) ? atomicAdd(&gcur[t], c) : 0;
    }
    __syncthreads();

#pragma unroll
    for (int u = 0; u < EPT; ++u) {
        if (iv[u] >= 0) {
            int bk  = iv[u] >> 8;
            int dst = gbase[bk] + rk[u];
            if (dst < SCAP)                  // p(bucket overflow) ~ 0 at +10 sigma
                staging[bk * SCAP + dst] = ((iv[u] & 255) << 17) | jv[u];
        }
    }
}

// --- Phase A2: slotify — bucket's pairs -> per-node 16-slot rows + degree ---
// One block per bucket (391). LDS-bin ~2560 pairs into a 256x16 slot table,
// then write it out as contiguous 16KB bursts. This removes the ~25us binning
// tax that lived inside the fused kernel in r5-r8.
__global__ __launch_bounds__(256) void slotify(
    const int* __restrict__ gcur, const int* __restrict__ staging,
    int* __restrict__ noflow, int* __restrict__ oflow,
    int* __restrict__ deg_g, int* __restrict__ slot_g)
{
    __shared__ int lcnt[BNODES];
    __shared__ int lsl[BNODES * CAP];        // 16 KB

    const int tid = threadIdx.x;
    const int bk  = blockIdx.x;

    lcnt[tid] = 0;
    __syncthreads();

    int m = gcur[bk];
    if (m > SCAP) m = SCAP;
    const int sg = bk * SCAP;
    for (int t = tid; t < m; t += 256) {
        int pk  = staging[sg + t];
        int off = pk >> 17;                  // 0..255 within bucket
        int pos = atomicAdd(&lcnt[off], 1);
        if (pos < CAP) {
            lsl[(off << 4) + pos] = pk & 0x1FFFF;
        } else {
            int o = atomicAdd(noflow, 1);
            if (o < MAXO) {
                oflow[2 * o]     = (bk << 8) + off;   // global node id
                oflow[2 * o + 1] = pk & 0x1FFFF;      // source j
            }
        }
    }
    __syncthreads();

    const int node = (bk << 8) + tid;
    if (node < N_NODES) {
        deg_g[node] = lcnt[tid];
        int4* dst = reinterpret_cast<int4*>(slot_g + ((size_t)node << 4));
        const int4* src = reinterpret_cast<const int4*>(lsl + (tid << 4));
        dst[0] = src[0]; dst[1] = src[1]; dst[2] = src[2]; dst[3] = src[3];
    }
}

// --- Phase B (fused): gather mean + 64x64 matmul + bias ---------------------
// Block = 256 threads = 4 waves, one 64-node tile. NO binning phase here.
// Gather = r0's PROVEN pattern, 4x deeper: wave per node, lane = feature,
// 16 fully-unrolled SCALAR loads x[j*64+lane] (4B/lane). Scalar loads cost
// 1 VGPR per in-flight row (vs 4 for the float4 design whose 64-VGPR live
// set the compiler refused to hold, r5-r8: VGPR=44, ~3 rows in flight).
// At 16 VGPRs of payload the scheduler clusters all 16 loads. deg is
// wave-uniform -> no divergence; u>=deg loads clamp to row 0 (L1-hot).
__global__ __launch_bounds__(256) void fused_gather_mm(
    const float* __restrict__ x, const int* __restrict__ deg_g,
    const int* __restrict__ slot_g,
    const float* __restrict__ W, const float* __restrict__ b,
    float* __restrict__ out)
{
    __shared__ float tile[TILE * PAD];       // 16.6 KB
    __shared__ int   lslot[TILE * CAP];      // 4 KB
    __shared__ int   ldeg[TILE];

    const int tid  = threadIdx.x;
    const int base = blockIdx.x * TILE;
    const int lane = tid & 63;
    const int wid  = tid >> 6;               // 0..3

    // stage the block's 64 slot rows (4 KB) + degrees, coalesced
    {
        const int4 v = *reinterpret_cast<const int4*>(
            slot_g + ((size_t)base << 4) + (tid << 2));   // slot_g padded
        *reinterpret_cast<int4*>(lslot + (tid << 2)) = v;
        if (tid < TILE) {
            int g = base + tid;
            ldeg[tid] = (g < N_NODES) ? deg_g[g] : 0;
        }
    }
    __syncthreads();

    // ---- gather: wave processes its 16 nodes; 16 scalar loads in flight ----
    for (int i = 0; i < 16; ++i) {
        const int row    = wid * 16 + i;     // 0..63
        const int d_true = ldeg[row];        // wave-uniform
        const int dd     = (d_true < CAP) ? d_true : CAP;

        float v[16];
#pragma unroll
        for (int u = 0; u < 16; ++u) {
            const int ju = lslot[(row << 4) + u];   // uniform addr -> broadcast
            const int jj = (u < dd) ? ju : 0;       // clamp: row 0, L1-hot
            v[u] = x[((size_t)jj << 6) + lane];
        }

        // zero-select then tree sum (dd uniform -> cheap selects)
        float s = 0.0f;
#pragma unroll
        for (int u = 0; u < 16; ++u)
            s += (u < dd) ? v[u] : 0.0f;

        const float inv = (d_true > 0) ? 1.0f / (float)d_true : 0.0f;
        tile[row * PAD + lane] = s * inv;    // (row+lane)%32: 2-way, free
    }
    __syncthreads();

    // ---- matmul: acc[q] = sum_k agg[nd][k] * W[d0+q][k] ----
    const int nd  = tid & 63;
    const int d0u = __builtin_amdgcn_readfirstlane((tid >> 6) << 4);
    const float* __restrict__ Wr = W + (size_t)d0u * DIM;   // uniform -> s_load

    float acc[16];
#pragma unroll
    for (int q = 0; q < 16; ++q) acc[q] = 0.0f;

#pragma unroll 4
    for (int k = 0; k < DIM; ++k) {
        float a = tile[nd * PAD + k];        // lane*65+k: conflict-free
#pragma unroll
        for (int q = 0; q < 16; ++q)
            acc[q] = fmaf(a, Wr[(size_t)q * DIM + k], acc[q]);
    }

    // ---- epilogue: mask + bias, LDS round-trip for coalesced store ----
    const int dg = ldeg[nd];
    __syncthreads();                         // everyone done reading agg
#pragma unroll
    for (int q = 0; q < 16; ++q) {
        float v2 = (dg > 0) ? (acc[q] + b[d0u + q]) : 0.0f;
        tile[nd * PAD + d0u + q] = v2;
    }
    __syncthreads();

#pragma unroll
    for (int r = 0; r < 16; ++r) {
        int idx = r * 256 + tid;             // 0..4095
        int row = idx >> 6, d = idx & 63;
        int g = base + row;
        if (g < N_NODES)
            out[(size_t)g * DIM + d] = tile[row * PAD + d];
    }
}

// --- Phase C: exact fixup for deg>16 overflow (~8k edges expected) ----------
__global__ __launch_bounds__(256) void fixup_overflow(
    const int* __restrict__ noflow, const int* __restrict__ oflow,
    const int* __restrict__ deg_g, const float* __restrict__ x,
    const float* __restrict__ W, float* __restrict__ out)
{
    int m = *noflow;
    if (m > MAXO) m = MAXO;
    const int lane = threadIdx.x & 63;
    const int wv   = (blockIdx.x * 256 + threadIdx.x) >> 6;
    const int nwv  = (gridDim.x * 256) >> 6;
    const float* __restrict__ wr = W + ((size_t)lane << 6);
    for (int o = wv; o < m; o += nwv) {
        const int i = oflow[2 * o];
        const int j = oflow[2 * o + 1];
        const float inv = 1.0f / (float)deg_g[i];
        const float* __restrict__ xr = x + ((size_t)j << 6);
        float acc = 0.0f;
#pragma unroll
        for (int k4 = 0; k4 < 16; ++k4) {
            const float4 xv  = *reinterpret_cast<const float4*>(xr + 4 * k4);
            const float4 wv4 = *reinterpret_cast<const float4*>(wr + 4 * k4);
            acc = fmaf(xv.x, wv4.x, acc);
            acc = fmaf(xv.y, wv4.y, acc);
            acc = fmaf(xv.z, wv4.z, acc);
            acc = fmaf(xv.w, wv4.w, acc);
        }
        atomicAdd(&out[((size_t)i << 6) + lane], acc * inv);
    }
}

extern "C" void kernel_launch(void* const* d_in, const int* in_sizes, int n_in,
                              void* d_out, int out_size, void* d_ws, size_t ws_size,
                              hipStream_t stream) {
    const float* x  = (const float*)d_in[0];   // (N, 64)
    const int*   ei = (const int*)d_in[1];     // (2, E): [0,E) targets, [E,2E) sources
    const float* W  = (const float*)d_in[2];   // (64, 64)
    const float* b  = (const float*)d_in[3];   // (64,)
    float* out = (float*)d_out;                // (N, 64)

    // Workspace layout (~11.2 MB)
    int* gcur    = (int*)d_ws;                 // NBUCK   (memset with noflow)
    int* noflow  = gcur + NBUCK;               // 1
    int* oflow   = noflow + 1;                 // 2*MAXO
    int* deg_g   = oflow + 2 * MAXO;           // N_NODES
    int* slot_g  = deg_g + N_NODES;            // N_NODES*16 + 1024 pad
    int* staging = slot_g + N_NODES * 16 + 1024;   // NBUCK * SCAP

    hipMemsetAsync(gcur, 0, (NBUCK + 1) * sizeof(int), stream);

    bin_edges<<<NWG_A, 256, 0, stream>>>(ei, gcur, staging);
    slotify<<<NBUCK, 256, 0, stream>>>(gcur, staging, noflow, oflow, deg_g, slot_g);
    fused_gather_mm<<<(N_NODES + TILE - 1) / TILE, 256, 0, stream>>>(
        x, deg_g, slot_g, W, b, out);
    fixup_overflow<<<128, 256, 0, stream>>>(noflow, oflow, deg_g, x, W, out);
}